// Round 3
// baseline (1438.761 us; speedup 1.0000x reference)
//
#include <hip/hip_runtime.h>
#include <hip/hip_bf16.h>
#include <math.h>

// ---------------------------------------------------------------------------
// CustomAutoencoder forward, fp32.
//   encoder: 4x conv(k3,s2,p1)+relu -> FC chain (custom tanh layer) ->
//   decoder: 4x convT(k3,s2,p1,op1)
// ConvT gather: out[oy][ox] += x[(oy+1-ky)/2][(ox+1-kx)/2] * w[ic][oc][ky][kx]
//   even out row 2i  : ky=1 <- x row i
//   odd  out row 2i+1: ky=2 <- x row i,  ky=0 <- x row i+1     (cols identical)
//
// ws_size-adaptive: batch is processed in chunks of C samples so peak scratch
// = B*2432 + C*331776 floats; C picked largest that fits ws_size.
// ---------------------------------------------------------------------------

// ------------------------------ conv k3 s2 p1 + relu -----------------------
template <int IC, int OC, int IH, int IW>
__global__ __launch_bounds__(256) void conv_k(const float* __restrict__ x,
                                              const float* __restrict__ w,
                                              const float* __restrict__ b,
                                              float* __restrict__ y, int B) {
    constexpr int OH = IH / 2, OW = IW / 2;
    __shared__ float wlds[IC * 9 * OC];
    for (int t = threadIdx.x; t < IC * 9 * OC; t += blockDim.x) {
        int oc = t % OC;
        int r = t / OC;
        int tap = r % 9;
        int ic = r / 9;
        wlds[t] = w[(oc * IC + ic) * 9 + tap];
    }
    __syncthreads();

    int idx = blockIdx.x * blockDim.x + threadIdx.x;
    if (idx >= B * OH * OW) return;
    int ox = idx % OW;
    int t2 = idx / OW;
    int oy = t2 % OH;
    int n = t2 / OH;

    const float* xn = x + (size_t)n * IC * IH * IW;
    float acc[OC];
#pragma unroll
    for (int oc = 0; oc < OC; oc++) acc[oc] = b[oc];

#pragma unroll 2
    for (int ic = 0; ic < IC; ic++) {
        float xv[9];
#pragma unroll
        for (int ky = 0; ky < 3; ky++) {
            int iy = 2 * oy - 1 + ky;
#pragma unroll
            for (int kx = 0; kx < 3; kx++) {
                int ix = 2 * ox - 1 + kx;
                bool ok = (iy >= 0) && (iy < IH) && (ix >= 0) && (ix < IW);
                xv[ky * 3 + kx] = ok ? xn[((size_t)ic * IH + iy) * IW + ix] : 0.f;
            }
        }
#pragma unroll
        for (int t3 = 0; t3 < 9; t3++) {
            if constexpr (OC % 4 == 0) {
                const float4* wr = (const float4*)(wlds + ((size_t)ic * 9 + t3) * OC);
#pragma unroll
                for (int o4 = 0; o4 < OC / 4; o4++) {
                    float4 wv = wr[o4];
                    acc[4 * o4 + 0] = fmaf(xv[t3], wv.x, acc[4 * o4 + 0]);
                    acc[4 * o4 + 1] = fmaf(xv[t3], wv.y, acc[4 * o4 + 1]);
                    acc[4 * o4 + 2] = fmaf(xv[t3], wv.z, acc[4 * o4 + 2]);
                    acc[4 * o4 + 3] = fmaf(xv[t3], wv.w, acc[4 * o4 + 3]);
                }
            } else {
#pragma unroll
                for (int oc = 0; oc < OC; oc++)
                    acc[oc] = fmaf(xv[t3], wlds[(ic * 9 + t3) * OC + oc], acc[oc]);
            }
        }
    }
    float* yn = y + (size_t)n * OC * OH * OW + (size_t)oy * OW + ox;
#pragma unroll
    for (int oc = 0; oc < OC; oc++) yn[(size_t)oc * OH * OW] = fmaxf(acc[oc], 0.f);
}

// ---------------- deconv, full 2x2 parity fuse (dc1, dc2) ------------------
template <int IC, int OC, int IH>
__global__ __launch_bounds__(256, 2) void deconv_full_k(const float* __restrict__ x,
                                                        const float* __restrict__ w,
                                                        const float* __restrict__ bias,
                                                        float* __restrict__ y, int B) {
    constexpr int IW = IH, OH = 2 * IH, OW = 2 * IH;
    __shared__ float wlds[IC * 9 * OC];  // [ic][tap][oc]
    for (int t = threadIdx.x; t < IC * 9 * OC; t += blockDim.x) {
        int oc = t % OC;
        int r = t / OC;
        int tap = r % 9;
        int ic = r / 9;
        wlds[t] = w[(ic * OC + oc) * 9 + tap];
    }
    __syncthreads();

    int idx = blockIdx.x * blockDim.x + threadIdx.x;
    if (idx >= B * IH * IW) return;
    int j = idx % IW;
    int t2 = idx / IW;
    int i = t2 % IH;
    int n = t2 / IH;

    const float* xn = x + (size_t)n * IC * IH * IW;
    float acc[2][2][OC];
#pragma unroll
    for (int oc = 0; oc < OC; oc++) {
        float bv = bias[oc];
        acc[0][0][oc] = bv;
        acc[0][1][oc] = bv;
        acc[1][0][oc] = bv;
        acc[1][1][oc] = bv;
    }
    const bool jok = (j + 1 < IW);

    constexpr int EDY[9] = {0, 0, 0, 0, 0, 0, 1, 1, 1};
    constexpr int EDX[9] = {0, 0, 0, 0, 1, 1, 0, 0, 1};
    constexpr int ERY[9] = {0, 0, 1, 1, 0, 1, 1, 1, 1};
    constexpr int ERX[9] = {0, 1, 0, 1, 1, 1, 0, 1, 1};
    constexpr int ETAP[9] = {4, 5, 7, 8, 3, 6, 1, 2, 0};  // ky*3+kx

#pragma unroll 2
    for (int ic = 0; ic < IC; ic++) {
        const float* r0p = xn + ((size_t)ic * IH + i) * IW + j;
        const bool iok = (i + 1 < IH);
        float xv[2][2];
        xv[0][0] = r0p[0];
        xv[0][1] = jok ? r0p[1] : 0.f;
        xv[1][0] = iok ? r0p[IW] : 0.f;
        xv[1][1] = (iok && jok) ? r0p[IW + 1] : 0.f;
#pragma unroll
        for (int e = 0; e < 9; e++) {
            float xval = xv[EDY[e]][EDX[e]];
            const float4* wr = (const float4*)(wlds + ((size_t)ic * 9 + ETAP[e]) * OC);
#pragma unroll
            for (int o4 = 0; o4 < OC / 4; o4++) {
                float4 wv = wr[o4];
                acc[ERY[e]][ERX[e]][4 * o4 + 0] = fmaf(xval, wv.x, acc[ERY[e]][ERX[e]][4 * o4 + 0]);
                acc[ERY[e]][ERX[e]][4 * o4 + 1] = fmaf(xval, wv.y, acc[ERY[e]][ERX[e]][4 * o4 + 1]);
                acc[ERY[e]][ERX[e]][4 * o4 + 2] = fmaf(xval, wv.z, acc[ERY[e]][ERX[e]][4 * o4 + 2]);
                acc[ERY[e]][ERX[e]][4 * o4 + 3] = fmaf(xval, wv.w, acc[ERY[e]][ERX[e]][4 * o4 + 3]);
            }
        }
    }
    float* yb = y + ((size_t)n * OC * OH + 2 * i) * OW + 2 * j;
#pragma unroll
    for (int oc = 0; oc < OC; oc++) {
        float* yp = yb + (size_t)oc * OH * OW;
        *reinterpret_cast<float2*>(yp) = make_float2(acc[0][0][oc], acc[0][1][oc]);
        *reinterpret_cast<float2*>(yp + OW) = make_float2(acc[1][0][oc], acc[1][1][oc]);
    }
}

// ------- deconv, row-parity split + 2-col + OC-half (dc3: 32->64@32) -------
template <int IC, int OC, int OCH, int IH, int EY>
__global__ __launch_bounds__(256, 2) void deconv_row2_k(const float* __restrict__ x,
                                                        const float* __restrict__ w,
                                                        const float* __restrict__ bias,
                                                        float* __restrict__ y, int B) {
    constexpr int IW = IH, OH = 2 * IH, OW = 2 * IH, JP = IW / 2, NR = 1 + EY;
    __shared__ float wlds[IC * NR * 3 * OCH];  // [ic][r][kx][oc]
    const int ocb = blockIdx.y * OCH;
    for (int t = threadIdx.x; t < IC * NR * 3 * OCH; t += blockDim.x) {
        int oc = t % OCH;
        int rest = t / OCH;
        int kx = rest % 3;
        int r = (rest / 3) % NR;
        int ic = rest / (3 * NR);
        int ky = EY ? (r == 0 ? 2 : 0) : 1;  // r=0 <- x row i, r=1 <- x row i+1
        wlds[t] = w[((ic * OC + ocb + oc) * 3 + ky) * 3 + kx];
    }
    __syncthreads();

    int idx = blockIdx.x * blockDim.x + threadIdx.x;
    if (idx >= B * IH * JP) return;
    int jp = idx % JP;
    int t2 = idx / JP;
    int i = t2 % IH;
    int n = t2 / IH;

    const float* xn = x + (size_t)n * IC * IH * IW + 2 * jp;
    float acc[4][OCH];  // output cols 4jp .. 4jp+3
#pragma unroll
    for (int oc = 0; oc < OCH; oc++) {
        float bv = bias[ocb + oc];
        acc[0][oc] = bv;
        acc[1][oc] = bv;
        acc[2][oc] = bv;
        acc[3][oc] = bv;
    }
    const bool jok = (jp + 1 < JP);

#pragma unroll 2
    for (int ic = 0; ic < IC; ic++) {
        float xr[NR][3];
#pragma unroll
        for (int r = 0; r < NR; r++) {
            const float* rp = xn + ((size_t)ic * IH + i + r) * IW;
            bool rok = (r == 0) || (i + 1 < IH);
            xr[r][0] = rok ? rp[0] : 0.f;
            xr[r][1] = rok ? rp[1] : 0.f;
            xr[r][2] = (rok && jok) ? rp[2] : 0.f;
        }
#pragma unroll
        for (int r = 0; r < NR; r++) {
            const float* wb = wlds + (size_t)(ic * NR + r) * 3 * OCH;
#pragma unroll
            for (int o4 = 0; o4 < OCH / 4; o4++) {
                float4 w0 = ((const float4*)(wb))[o4];
                float4 w1 = ((const float4*)(wb + OCH))[o4];
                float4 w2 = ((const float4*)(wb + 2 * OCH))[o4];
#define Q(q, wq0, wq1, wq2)                                          \
    acc[0][4 * o4 + q] = fmaf(xr[r][0], wq1, acc[0][4 * o4 + q]);    \
    acc[1][4 * o4 + q] = fmaf(xr[r][0], wq2, acc[1][4 * o4 + q]);    \
    acc[1][4 * o4 + q] = fmaf(xr[r][1], wq0, acc[1][4 * o4 + q]);    \
    acc[2][4 * o4 + q] = fmaf(xr[r][1], wq1, acc[2][4 * o4 + q]);    \
    acc[3][4 * o4 + q] = fmaf(xr[r][1], wq2, acc[3][4 * o4 + q]);    \
    acc[3][4 * o4 + q] = fmaf(xr[r][2], wq0, acc[3][4 * o4 + q]);
                Q(0, w0.x, w1.x, w2.x)
                Q(1, w0.y, w1.y, w2.y)
                Q(2, w0.z, w1.z, w2.z)
                Q(3, w0.w, w1.w, w2.w)
#undef Q
            }
        }
    }
    float* yb = y + ((size_t)(n * OC + ocb) * OH + 2 * i + EY) * OW + 4 * jp;
#pragma unroll
    for (int oc = 0; oc < OCH; oc++) {
        *reinterpret_cast<float4*>(yb + (size_t)oc * OH * OW) =
            make_float4(acc[0][oc], acc[1][oc], acc[2][oc], acc[3][oc]);
    }
}

// ----------- deconv final (dc4: 64->3@64), OC padded to 4, 2-col -----------
__global__ __launch_bounds__(256, 4) void deconv_last_k(const float* __restrict__ x,
                                                        const float* __restrict__ w,
                                                        const float* __restrict__ bias,
                                                        float* __restrict__ y, int B) {
    constexpr int IC = 64, OCR = 3, IH = 64, IW = 64, OH = 128, OW = 128, JP = 32;
    __shared__ float wlds[IC * 9 * 4];  // [ic][tap][oc4]
    for (int t = threadIdx.x; t < IC * 9 * 4; t += blockDim.x) {
        int oc = t % 4;
        int rest = t / 4;
        int tap = rest % 9;
        int ic = rest / 9;
        wlds[t] = (oc < OCR) ? w[(ic * OCR + oc) * 9 + tap] : 0.f;
    }
    __syncthreads();

    int idx = blockIdx.x * blockDim.x + threadIdx.x;
    if (idx >= B * IH * JP) return;
    int jp = idx % JP;
    int t2 = idx / JP;
    int i = t2 % IH;
    int n = t2 / IH;

    const float* xn = x + (size_t)n * IC * IH * IW + 2 * jp;
    float b0 = bias[0], b1 = bias[1], b2 = bias[2];
    float acc[2][4][4];  // [ry][out col][oc4]
#pragma unroll
    for (int ry = 0; ry < 2; ry++)
#pragma unroll
        for (int c = 0; c < 4; c++) {
            acc[ry][c][0] = b0;
            acc[ry][c][1] = b1;
            acc[ry][c][2] = b2;
            acc[ry][c][3] = 0.f;
        }
    const bool jok = (jp + 1 < JP);

    constexpr int RDY[3] = {0, 0, 1};
    constexpr int RRY[3] = {0, 1, 1};
    constexpr int RKY[3] = {1, 2, 0};

#pragma unroll 4
    for (int ic = 0; ic < IC; ic++) {
        float xr[2][3];
#pragma unroll
        for (int r = 0; r < 2; r++) {
            const float* rp = xn + ((size_t)ic * IH + i + r) * IW;
            bool rok = (r == 0) || (i + 1 < IH);
            xr[r][0] = rok ? rp[0] : 0.f;
            xr[r][1] = rok ? rp[1] : 0.f;
            xr[r][2] = (rok && jok) ? rp[2] : 0.f;
        }
        const float4* w4 = (const float4*)(wlds) + ic * 9;
#pragma unroll
        for (int rc = 0; rc < 3; rc++) {
            float4 W0 = w4[RKY[rc] * 3 + 0];
            float4 W1 = w4[RKY[rc] * 3 + 1];
            float4 W2 = w4[RKY[rc] * 3 + 2];
            float x0 = xr[RDY[rc]][0], x1 = xr[RDY[rc]][1], x2 = xr[RDY[rc]][2];
#define QQ(c, xa, Wv)                                                \
    {                                                                \
        acc[RRY[rc]][c][0] = fmaf(xa, Wv.x, acc[RRY[rc]][c][0]);     \
        acc[RRY[rc]][c][1] = fmaf(xa, Wv.y, acc[RRY[rc]][c][1]);     \
        acc[RRY[rc]][c][2] = fmaf(xa, Wv.z, acc[RRY[rc]][c][2]);     \
        acc[RRY[rc]][c][3] = fmaf(xa, Wv.w, acc[RRY[rc]][c][3]);     \
    }
            QQ(0, x0, W1)
            QQ(1, x0, W2)
            QQ(1, x1, W0)
            QQ(2, x1, W1)
            QQ(3, x1, W2)
            QQ(3, x2, W0)
#undef QQ
        }
    }
#pragma unroll
    for (int oc = 0; oc < OCR; oc++) {
        float* yp = y + ((size_t)(n * OCR + oc) * OH + 2 * i) * OW + 4 * jp;
        *reinterpret_cast<float4*>(yp) =
            make_float4(acc[0][0][oc], acc[0][1][oc], acc[0][2][oc], acc[0][3][oc]);
        *reinterpret_cast<float4*>(yp + OW) =
            make_float4(acc[1][0][oc], acc[1][1][oc], acc[1][2][oc], acc[1][3][oc]);
    }
}

// ------------------------------ linear (+act) ------------------------------
template <int IN, int OUT, int ACT>  // ACT: 0 relu, 1 leaky(0.01)
__global__ __launch_bounds__(256) void linear_k(const float* __restrict__ h,
                                                const float* __restrict__ w,
                                                const float* __restrict__ b,
                                                float* __restrict__ y, int B) {
    int idx = blockIdx.x * blockDim.x + threadIdx.x;
    if (idx >= B * OUT) return;
    int o = idx % OUT;
    int n = idx / OUT;
    const float4* hr = (const float4*)(h + (size_t)n * IN);
    const float4* wr = (const float4*)(w + (size_t)o * IN);
    float acc = 0.f;
#pragma unroll 4
    for (int k = 0; k < IN / 4; k++) {
        float4 a = hr[k];
        float4 ww = wr[k];
        acc += a.x * ww.x + a.y * ww.y + a.z * ww.z + a.w * ww.w;
    }
    acc += b[o];
    y[idx] = (ACT == 0) ? fmaxf(acc, 0.f) : (acc > 0.f ? acc : 0.01f * acc);
}

// --------------------- CustomLayer: lin + tanh neuron ----------------------
__global__ __launch_bounds__(256) void custom_layer_k(
    const float* __restrict__ h, const float* __restrict__ clw, const float* __restrict__ clb,
    const float* __restrict__ nw, const float* __restrict__ nb, const float* __restrict__ low,
    const float* __restrict__ high, float* __restrict__ y, int B) {
    int idx = blockIdx.x * blockDim.x + threadIdx.x;
    if (idx >= B * 512) return;
    int o = idx % 512;
    int n = idx / 512;
    const float4* hr = (const float4*)(h + (size_t)n * 256);
    const float4* w1 = (const float4*)(clw + (size_t)o * 256);
    const float4* w2 = (const float4*)(nw + (size_t)o * 256);
    float lin = 0.f, z = 0.f;
#pragma unroll 4
    for (int k = 0; k < 64; k++) {
        float4 a = hr[k];
        float4 b1 = w1[k];
        float4 b2 = w2[k];
        lin += a.x * b1.x + a.y * b1.y + a.z * b1.z + a.w * b1.w;
        z += a.x * b2.x + a.y * b2.y + a.z * b2.z + a.w * b2.w;
    }
    lin += clb[o];
    z += nb[o];
    float neur = tanhf(tanhf(low[o] * z - high[o]));
    y[idx] = fmaxf(lin + neur, 0.f);
}

// ---------------------------------------------------------------------------
extern "C" void kernel_launch(void* const* d_in, const int* in_sizes, int n_in,
                              void* d_out, int out_size, void* d_ws, size_t ws_size,
                              hipStream_t stream) {
    const float* x = (const float*)d_in[0];
    const float* conv1_w = (const float*)d_in[1];
    const float* conv1_b = (const float*)d_in[2];
    const float* conv2_w = (const float*)d_in[3];
    const float* conv2_b = (const float*)d_in[4];
    const float* conv3_w = (const float*)d_in[5];
    const float* conv3_b = (const float*)d_in[6];
    const float* conv4_w = (const float*)d_in[7];
    const float* conv4_b = (const float*)d_in[8];
    const float* l2_w = (const float*)d_in[9];
    const float* l2_b = (const float*)d_in[10];
    const float* cl_w = (const float*)d_in[11];
    const float* cl_b = (const float*)d_in[12];
    const float* n_w = (const float*)d_in[13];
    const float* n_b = (const float*)d_in[14];
    const float* low = (const float*)d_in[15];
    const float* high = (const float*)d_in[16];
    const float* l4_w = (const float*)d_in[17];
    const float* l4_b = (const float*)d_in[18];
    const float* lL_w = (const float*)d_in[19];
    const float* lL_b = (const float*)d_in[20];
    const float* fc4_w = (const float*)d_in[21];
    const float* fc4_b = (const float*)d_in[22];
    const float* fc5_w = (const float*)d_in[23];
    const float* fc5_b = (const float*)d_in[24];
    const float* dc1_w = (const float*)d_in[25];
    const float* dc1_b = (const float*)d_in[26];
    const float* dc2_w = (const float*)d_in[27];
    const float* dc2_b = (const float*)d_in[28];
    const float* dc3_w = (const float*)d_in[29];
    const float* dc3_b = (const float*)d_in[30];
    const float* dc4_w = (const float*)d_in[31];
    const float* dc4_b = (const float*)d_in[32];

    const int B = in_sizes[0] / (3 * 128 * 128);  // 256
    float* out = (float*)d_out;
    float* ws = (float*)d_ws;
    const size_t WS = ws_size / sizeof(float);

    // --- persistent small FC buffers at the front of ws ---
    float* h4 = ws;                      // [B,128]
    float* h5 = h4 + (size_t)B * 128;    // [B,256]
    float* h6 = h5 + (size_t)B * 256;    // [B,512]
    float* h7 = h6 + (size_t)B * 512;    // [B,256]
    float* h8 = h7 + (size_t)B * 256;    // [B,256]
    float* h9 = h8 + (size_t)B * 256;    // [B,512]
    float* h10 = h9 + (size_t)B * 512;   // [B,512]
    const size_t small = (size_t)B * 2432;

    // --- pick largest chunk size C that fits: need = small + C*331776 ---
    // bufC: C*4096 (h3/d1)  bufA: C*65536 (h1/d2)  bufB: C*262144 (h2/d3)
    int C = 1;
    for (int cand = B; cand >= 1; cand >>= 1) {
        if (small + (size_t)cand * 331776 <= WS) { C = cand; break; }
        if (cand == 1) break;
    }
    float* bufC = ws + small;
    float* bufA = bufC + (size_t)C * 4096;
    float* bufB = bufA + (size_t)C * 65536;

    dim3 blk(256);
    auto cdiv = [](int a, int b) { return (a + b - 1) / b; };

    // ---------------- encoder, chunked ----------------
    for (int n0 = 0; n0 < B; n0 += C) {
        int Cc = (B - n0 < C) ? (B - n0) : C;
        conv_k<3, 16, 128, 128><<<dim3(cdiv(Cc * 64 * 64, 256)), blk, 0, stream>>>(
            x + (size_t)n0 * 3 * 128 * 128, conv1_w, conv1_b, bufA, Cc);
        conv_k<16, 8, 64, 64><<<dim3(cdiv(Cc * 32 * 32, 256)), blk, 0, stream>>>(
            bufA, conv2_w, conv2_b, bufB, Cc);
        conv_k<8, 4, 32, 32><<<dim3(cdiv(Cc * 16 * 16, 256)), blk, 0, stream>>>(
            bufB, conv3_w, conv3_b, bufC, Cc);
        conv_k<4, 2, 16, 16><<<dim3(cdiv(Cc * 8 * 8, 256)), blk, 0, stream>>>(
            bufC, conv4_w, conv4_b, h4 + (size_t)n0 * 128, Cc);
    }

    // ---------------- FC chain, full batch ----------------
    linear_k<128, 256, 0><<<dim3(cdiv(B * 256, 256)), blk, 0, stream>>>(h4, l2_w, l2_b, h5, B);
    custom_layer_k<<<dim3(cdiv(B * 512, 256)), blk, 0, stream>>>(h5, cl_w, cl_b, n_w, n_b, low,
                                                                 high, h6, B);
    linear_k<512, 256, 0><<<dim3(cdiv(B * 256, 256)), blk, 0, stream>>>(h6, l4_w, l4_b, h7, B);
    linear_k<256, 256, 1><<<dim3(cdiv(B * 256, 256)), blk, 0, stream>>>(h7, lL_w, lL_b, h8, B);
    linear_k<256, 512, 1><<<dim3(cdiv(B * 512, 256)), blk, 0, stream>>>(h8, fc4_w, fc4_b, h9, B);
    linear_k<512, 512, 0><<<dim3(cdiv(B * 512, 256)), blk, 0, stream>>>(h9, fc5_w, fc5_b, h10, B);

    // ---------------- decoder, chunked ----------------
    for (int n0 = 0; n0 < B; n0 += C) {
        int Cc = (B - n0 < C) ? (B - n0) : C;
        deconv_full_k<8, 16, 8><<<dim3(cdiv(Cc * 8 * 8, 256)), blk, 0, stream>>>(
            h10 + (size_t)n0 * 512, dc1_w, dc1_b, bufC, Cc);
        deconv_full_k<16, 32, 16><<<dim3(cdiv(Cc * 16 * 16, 256)), blk, 0, stream>>>(
            bufC, dc2_w, dc2_b, bufA, Cc);
        deconv_row2_k<32, 64, 32, 32, 0><<<dim3(cdiv(Cc * 32 * 16, 256), 2), blk, 0, stream>>>(
            bufA, dc3_w, dc3_b, bufB, Cc);
        deconv_row2_k<32, 64, 32, 32, 1><<<dim3(cdiv(Cc * 32 * 16, 256), 2), blk, 0, stream>>>(
            bufA, dc3_w, dc3_b, bufB, Cc);
        deconv_last_k<<<dim3(cdiv(Cc * 64 * 32, 256)), blk, 0, stream>>>(
            bufB, dc4_w, dc4_b, out + (size_t)n0 * 3 * 128 * 128, Cc);
    }
}